// Round 1
// baseline (261.869 us; speedup 1.0000x reference)
//
#include <hip/hip_runtime.h>
#include <math.h>

#define Bsz 64
#define Tn 200
#define NUMC 2000
#define DS 128
#define SM 50
#define NTOK (Bsz*Tn)
#define TT 16        // tokens per block in k1/k3
#define WG 5         // m-groups in scan
#define MPG 10       // m per group (WG*MPG == SM)

// ---------------- K1: gather + w logits/softmax + e + a + kpart ----------------
// block = 256 threads, TT tokens. Thread slotA: o<128 -> e row (input v), o>=128 -> a row (input v).
// Thread slotB: o<128 -> f_W[o, 128:256] (kpart, input k), 128<=o<178 -> Mk row (w logit, input k).
__global__ __launch_bounds__(256) void k1_prep(
    const int* __restrict__ skill, const int* __restrict__ answer,
    const float* __restrict__ k_emb, const float* __restrict__ v_emb,
    const float* __restrict__ Mk,
    const float* __restrict__ eW, const float* __restrict__ eB,
    const float* __restrict__ aW, const float* __restrict__ aB,
    const float* __restrict__ fW,
    float* __restrict__ w_buf, float* __restrict__ e_buf,
    float* __restrict__ a_buf, float* __restrict__ kp_buf)
{
    const int tid  = threadIdx.x;
    const int tok0 = blockIdx.x * TT;

    const float* rowA = (tid < DS) ? (eW + (size_t)tid * DS)
                                   : (aW + (size_t)(tid - DS) * DS);
    const float* rowB = (tid < DS) ? (fW + (size_t)tid * (2*DS) + DS)
                   : ((tid < DS + SM) ? (Mk + (size_t)(tid - DS) * DS) : fW);

    float accA[TT], accB[TT];
    #pragma unroll
    for (int i = 0; i < TT; i++) { accA[i] = 0.f; accB[i] = 0.f; }

    // wave-uniform token row bases -> force SGPR so inner loads scalarize
    int sbase[TT], xbase[TT];
    #pragma unroll
    for (int i = 0; i < TT; i++) {
        const int tf = tok0 + i;
        int s  = skill[tf];
        int an = answer[tf];
        int ax = (an == 2) ? 1 : an;
        sbase[i] = __builtin_amdgcn_readfirstlane(s * DS);
        xbase[i] = __builtin_amdgcn_readfirstlane((s + NUMC * ax) * DS);
    }

    for (int c = 0; c < 4; c++) {
        const int d0 = c * 32;
        float wA[32], wB[32];
        #pragma unroll
        for (int j = 0; j < 32; j += 4) {
            float4 ta = *(const float4*)(rowA + d0 + j);
            wA[j]=ta.x; wA[j+1]=ta.y; wA[j+2]=ta.z; wA[j+3]=ta.w;
            float4 tb = *(const float4*)(rowB + d0 + j);
            wB[j]=tb.x; wB[j+1]=tb.y; wB[j+2]=tb.z; wB[j+3]=tb.w;
        }
        #pragma unroll 4
        for (int i = 0; i < TT; i++) {
            const float* kr = k_emb + sbase[i] + d0;   // uniform -> s_load
            const float* vr = v_emb + xbase[i] + d0;   // uniform -> s_load
            float a0=0.f, a1=0.f, b0=0.f, b1=0.f;
            #pragma unroll
            for (int j = 0; j < 32; j += 2) {
                a0 = fmaf(wA[j],   vr[j],   a0);
                a1 = fmaf(wA[j+1], vr[j+1], a1);
                b0 = fmaf(wB[j],   kr[j],   b0);
                b1 = fmaf(wB[j+1], kr[j+1], b1);
            }
            accA[i] += a0 + a1;
            accB[i] += b0 + b1;
        }
    }

    __shared__ float wl[TT][SM];
    __shared__ float wpb[TT][SM];

    #pragma unroll
    for (int i = 0; i < TT; i++) {
        const int tf = tok0 + i;
        if (tid < DS) {
            float ev = accA[i] + eB[tid];
            e_buf[(size_t)tf*DS + tid]  = 1.f / (1.f + expf(-ev));
            kp_buf[(size_t)tf*DS + tid] = accB[i];
        } else {
            const int o = tid - DS;
            a_buf[(size_t)tf*DS + o] = tanhf(accA[i] + aB[o]);
            if (o < SM) wl[i][o] = accB[i];
        }
    }
    __syncthreads();
    if (tid < TT) {
        float mx = -1e30f;
        for (int m = 0; m < SM; m++) mx = fmaxf(mx, wl[tid][m]);
        float sum = 0.f;
        for (int m = 0; m < SM; m++) { float ex = expf(wl[tid][m] - mx); wpb[tid][m] = ex; sum += ex; }
        const float inv = 1.f / sum;
        for (int m = 0; m < SM; m++) wpb[tid][m] *= inv;
    }
    __syncthreads();
    for (int idx = tid; idx < TT * SM; idx += 256) {
        const int i = idx / SM, m = idx % SM;
        w_buf[(size_t)(tok0 + i) * SM + m] = wpb[i][m];
    }
}

// ---------------- K2: the sequential scan, split over (b, d-half, m-group) ----------------
// One wave per block; lane owns d; Mv slice in registers; no LDS, no barriers.
// Partial reads (sum over this wave's m-subset) written to part_buf[mg].
__global__ __launch_bounds__(64) void k2_scan(
    const float* __restrict__ w_buf, const float* __restrict__ e_buf,
    const float* __restrict__ a_buf, const float* __restrict__ Mv0,
    float* __restrict__ part_buf)
{
    const int bi   = blockIdx.x;
    const int b    = bi / (2*WG);
    const int r    = bi % (2*WG);
    const int dh   = r / WG;
    const int mg   = r % WG;
    const int lane = threadIdx.x;
    const int d    = dh*64 + lane;
    const int m0   = mg * MPG;
    const int base = b * Tn;

    float Mv[MPG];
    #pragma unroll
    for (int m = 0; m < MPG; m++) Mv[m] = Mv0[(size_t)(m0+m)*DS + d];

    float* pout = part_buf + (size_t)mg * NTOK * DS;

    // 4-deep prefetch pipeline
    float ev0[4], av0[4], wv0[4][MPG];
    #pragma unroll
    for (int q = 0; q < 4; q++) {
        const int tf = base + q;
        ev0[q] = e_buf[(size_t)tf*DS + d];
        av0[q] = a_buf[(size_t)tf*DS + d];
        #pragma unroll
        for (int m = 0; m < MPG; m++) wv0[q][m] = w_buf[(size_t)tf*SM + m0 + m];
    }

    for (int tb = 0; tb < Tn; tb += 4) {
        float ev1[4] = {}, av1[4] = {}, wv1[4][MPG] = {};
        if (tb + 4 < Tn) {
            #pragma unroll
            for (int q = 0; q < 4; q++) {
                const int tf = base + tb + 4 + q;
                ev1[q] = e_buf[(size_t)tf*DS + d];
                av1[q] = a_buf[(size_t)tf*DS + d];
                #pragma unroll
                for (int m = 0; m < MPG; m++) wv1[q][m] = w_buf[(size_t)tf*SM + m0 + m];
            }
        }
        #pragma unroll
        for (int q = 0; q < 4; q++) {
            float rd = 0.f;
            #pragma unroll
            for (int m = 0; m < MPG; m++) {
                const float wm = wv0[q][m];
                rd = fmaf(wm, Mv[m], rd);                              // read uses OLD Mv
                Mv[m] = fmaf(-wm, fmaf(ev0[q], Mv[m], -av0[q]), Mv[m]); // Mv*(1-w*e)+w*a
            }
            pout[(size_t)(base + tb + q)*DS + d] = rd;
        }
        #pragma unroll
        for (int q = 0; q < 4; q++) {
            ev0[q] = ev1[q]; av0[q] = av1[q];
            #pragma unroll
            for (int m = 0; m < MPG; m++) wv0[q][m] = wv1[q][m];
        }
    }
}

// ---------------- K2.5: sum the WG partial-read buffers ----------------
__global__ __launch_bounds__(256) void k25_combine(
    const float4* __restrict__ part, float4* __restrict__ reads)
{
    const int N4 = NTOK * DS / 4;
    const int i = blockIdx.x * 256 + threadIdx.x;
    if (i < N4) {
        float4 s = part[i];
        #pragma unroll
        for (int g = 1; g < WG; g++) {
            float4 p = part[(size_t)g * N4 + i];
            s.x += p.x; s.y += p.y; s.z += p.z; s.w += p.w;
        }
        reads[i] = s;
    }
}

// ---------------- K3: f = tanh(reads@fW[:,:128]^T + kpart + f_b); pred gather-dot ----------------
// block = 128 threads (2 waves), thread = output o, TT tokens.
__global__ __launch_bounds__(128) void k3_out(
    const float* __restrict__ reads, const float* __restrict__ kp_buf,
    const float* __restrict__ fW, const float* __restrict__ fB,
    const float* __restrict__ pW, const float* __restrict__ pB,
    const int* __restrict__ skill, float* __restrict__ out)
{
    const int tid  = threadIdx.x;      // output o
    const int tok0 = blockIdx.x * TT;

    float acc[TT];
    #pragma unroll
    for (int i = 0; i < TT; i++) acc[i] = 0.f;

    for (int c = 0; c < 4; c++) {
        const int d0 = c * 32;
        float wr[32];
        #pragma unroll
        for (int j = 0; j < 32; j += 4) {
            float4 t4 = *(const float4*)(fW + (size_t)tid*(2*DS) + d0 + j);
            wr[j]=t4.x; wr[j+1]=t4.y; wr[j+2]=t4.z; wr[j+3]=t4.w;
        }
        #pragma unroll 4
        for (int i = 0; i < TT; i++) {
            const float* rp = reads + (size_t)(tok0+i)*DS + d0;   // uniform -> s_load
            float s0=0.f, s1=0.f;
            #pragma unroll
            for (int j = 0; j < 32; j += 2) {
                s0 = fmaf(wr[j],   rp[j],   s0);
                s1 = fmaf(wr[j+1], rp[j+1], s1);
            }
            acc[i] += s0 + s1;
        }
    }

    __shared__ float red[TT][2];
    const float fb = fB[tid];
    const int wid = tid >> 6;

    #pragma unroll
    for (int i = 0; i < TT; i++) {
        const int tf = tok0 + i;
        const int t  = tf % Tn;
        float fo = tanhf(acc[i] + kp_buf[(size_t)tf*DS + tid] + fb);
        float contrib = 0.f;
        if (t < Tn - 1) {
            int sn = skill[tf + 1];
            int ix = (sn < NUMC) ? sn : (NUMC - 1);
            contrib = fo * pW[(size_t)ix*DS + tid];
        }
        #pragma unroll
        for (int msk = 32; msk > 0; msk >>= 1)
            contrib += __shfl_xor(contrib, msk);
        if ((tid & 63) == 0) red[i][wid] = contrib;
    }
    __syncthreads();
    if (tid < TT) {
        const int tf = tok0 + tid;
        const int t  = tf % Tn;
        if (t < Tn - 1) {
            int sn = skill[tf + 1];
            int ix = (sn < NUMC) ? sn : (NUMC - 1);
            float val = red[tid][0] + red[tid][1] + pB[ix];
            float pr = (sn < NUMC) ? (1.f / (1.f + expf(-val))) : 0.f;
            out[(size_t)(tf / Tn) * (Tn - 1) + t] = pr;
        }
    }
}

extern "C" void kernel_launch(void* const* d_in, const int* in_sizes, int n_in,
                              void* d_out, int out_size, void* d_ws, size_t ws_size,
                              hipStream_t stream)
{
    const int*   skill  = (const int*)  d_in[0];
    const int*   answer = (const int*)  d_in[1];
    const float* k_emb  = (const float*)d_in[2];
    const float* v_emb  = (const float*)d_in[3];
    const float* Mk     = (const float*)d_in[4];
    const float* Mv0    = (const float*)d_in[5];
    const float* f_W    = (const float*)d_in[6];
    const float* f_b    = (const float*)d_in[7];
    const float* p_W    = (const float*)d_in[8];
    const float* p_b    = (const float*)d_in[9];
    const float* e_W    = (const float*)d_in[10];
    const float* e_b    = (const float*)d_in[11];
    const float* a_W    = (const float*)d_in[12];
    const float* a_b    = (const float*)d_in[13];
    float* out = (float*)d_out;

    float* ws       = (float*)d_ws;
    float* w_buf    = ws;                                  // NTOK*SM      = 640000
    float* e_buf    = w_buf    + (size_t)NTOK*SM;          // NTOK*DS      = 1638400
    float* a_buf    = e_buf    + (size_t)NTOK*DS;
    float* kp_buf   = a_buf    + (size_t)NTOK*DS;
    float* part_buf = kp_buf   + (size_t)NTOK*DS;          // WG*NTOK*DS   = 8192000
    float* reads_buf= part_buf + (size_t)WG*NTOK*DS;       // NTOK*DS
    // total ~61.5 MB of d_ws

    k1_prep<<<NTOK/TT, 256, 0, stream>>>(skill, answer, k_emb, v_emb, Mk,
        e_W, e_b, a_W, a_b, f_W, w_buf, e_buf, a_buf, kp_buf);
    k2_scan<<<Bsz*2*WG, 64, 0, stream>>>(w_buf, e_buf, a_buf, Mv0, part_buf);
    const int n4 = NTOK*DS/4;
    k25_combine<<<(n4+255)/256, 256, 0, stream>>>((const float4*)part_buf, (float4*)reads_buf);
    k3_out<<<NTOK/TT, 128, 0, stream>>>(reads_buf, kp_buf, f_W, f_b, p_W, p_b, skill, out);
}

// Round 2
// 165.817 us; speedup vs baseline: 1.5793x; 1.5793x over previous
//
#include <hip/hip_runtime.h>
#include <math.h>

#define Bsz 64
#define Tn 200
#define NUMC 2000
#define DS 128
#define SM 50
#define NTOK (Bsz*Tn)
#define WG 5         // m-groups in scan
#define MPG 10       // m per group (WG*MPG == SM)

typedef __attribute__((ext_vector_type(8))) short bfrag;
typedef __attribute__((ext_vector_type(4))) float f32x4;
typedef __attribute__((ext_vector_type(4))) unsigned int u32x4;

__device__ __forceinline__ unsigned short f2bf(float x) {
    unsigned int u = __builtin_bit_cast(unsigned int, x);
    u = u + 0x7fffu + ((u >> 16) & 1u);   // RNE
    return (unsigned short)(u >> 16);
}
__device__ __forceinline__ unsigned int pack2(float a, float b) {
    return (unsigned int)f2bf(a) | ((unsigned int)f2bf(b) << 16);
}
__device__ __forceinline__ bfrag mk_frag(f32x4 x, f32x4 y) {
    u32x4 t;
    t[0] = pack2(x[0], x[1]); t[1] = pack2(x[2], x[3]);
    t[2] = pack2(y[0], y[1]); t[3] = pack2(y[2], y[3]);
    return __builtin_bit_cast(bfrag, t);
}

// ---------------- K0: cast weights into MFMA b-frag block layout ----------------
// Chunk layout per matrix: for (nt, ki): 64 lanes x 8 bf16 contiguous (1KB chunk).
// lane L holds W[n = nt*16 + (L&15)][k = ki*32 + (L>>4)*8 + j], j=0..7.
// Bea: rows 0-127 = e_W, 128-255 = a_W          (16 n-tiles)
// Bkm: rows 0-127 = f_W[:,128:256], 128-177 = Mk, 178-191 = 0   (12 n-tiles)
// Bf0: rows 0-127 = f_W[:,0:128]                (8 n-tiles)
__global__ __launch_bounds__(256) void k0_cast(
    const float* __restrict__ eW, const float* __restrict__ aW,
    const float* __restrict__ fW, const float* __restrict__ Mk,
    unsigned int* __restrict__ BeaU, unsigned int* __restrict__ BkmU,
    unsigned int* __restrict__ Bf0U)
{
    const int g = blockIdx.x * 256 + threadIdx.x;
    if (g >= 9216) return;
    int gm, mat;
    unsigned int* dst;
    if (g < 4096)      { mat = 0; gm = g;        dst = BeaU; }
    else if (g < 7168) { mat = 1; gm = g - 4096; dst = BkmU; }
    else               { mat = 2; gm = g - 7168; dst = Bf0U; }
    const int nt = gm >> 8, r = gm & 255, ki = r >> 6, L = r & 63;
    const int n = nt * 16 + (L & 15);
    const int k = ki * 32 + (L >> 4) * 8;

    const float* src = nullptr;
    if (mat == 0) {
        src = (n < 128) ? (eW + (size_t)n * DS + k) : (aW + (size_t)(n - 128) * DS + k);
    } else if (mat == 1) {
        if (n < 128)      src = fW + (size_t)n * (2 * DS) + DS + k;
        else if (n < 128 + SM) src = Mk + (size_t)(n - 128) * DS + k;
    } else {
        src = fW + (size_t)n * (2 * DS) + k;
    }
    float v[8];
    #pragma unroll
    for (int j = 0; j < 8; j++) v[j] = src ? src[j] : 0.f;
    u32x4 o;
    o[0] = pack2(v[0], v[1]); o[1] = pack2(v[2], v[3]);
    o[2] = pack2(v[4], v[5]); o[3] = pack2(v[6], v[7]);
    ((u32x4*)dst)[gm] = o;
}

// ---------------- K1: gather + two bf16 MFMA GEMMs + softmax ----------------
// block = 4 waves, 64 tokens; wave w owns m-tile of 16 tokens.
// GEMM-EA: V(16x128) @ Bea^T -> e (sigmoid), a (tanh)
// GEMM-KM: K(16x128) @ Bkm^T -> kpart, w-logits -> softmax -> w
__global__ __launch_bounds__(256) void k1_gemm(
    const int* __restrict__ skill, const int* __restrict__ answer,
    const float* __restrict__ k_emb, const float* __restrict__ v_emb,
    const unsigned int* __restrict__ BeaU, const unsigned int* __restrict__ BkmU,
    const float* __restrict__ eB, const float* __restrict__ aB,
    float* __restrict__ w_buf, float* __restrict__ e_buf,
    float* __restrict__ a_buf, float* __restrict__ kp_buf)
{
    const int tid = threadIdx.x;
    const int w = tid >> 6, L = tid & 63, L15 = L & 15, quad = L >> 4;
    const int tok0 = blockIdx.x * 64;
    const int tokA = tok0 + 16 * w + L15;       // A-operand row this lane loads
    const int tokD0 = tok0 + 16 * w + quad * 4; // D rows: tokD0 + reg

    const int s  = skill[tokA];
    const int an = answer[tokA];
    const int ax = (an == 2) ? 1 : an;
    const float* vp = v_emb + ((size_t)(s + NUMC * ax)) * DS + quad * 8;
    const float* kp = k_emb + (size_t)s * DS + quad * 8;

    bfrag Vf[4], Kf[4];
    #pragma unroll
    for (int ki = 0; ki < 4; ki++) {
        const f32x4* a = (const f32x4*)(vp + ki * 32);
        Vf[ki] = mk_frag(a[0], a[1]);
        const f32x4* b = (const f32x4*)(kp + ki * 32);
        Kf[ki] = mk_frag(b[0], b[1]);
    }

    const bfrag* Bea = (const bfrag*)BeaU;
    const bfrag* Bkm = (const bfrag*)BkmU;

    __shared__ float wl[64][52];

    // ---- GEMM-EA: 16 n-tiles, groups of 4 for ILP ----
    for (int nt0 = 0; nt0 < 16; nt0 += 4) {
        bfrag bf[4][4];
        #pragma unroll
        for (int t = 0; t < 4; t++)
            #pragma unroll
            for (int ki = 0; ki < 4; ki++)
                bf[t][ki] = Bea[(size_t)((nt0 + t) * 4 + ki) * 64 + L];
        f32x4 acc[4];
        #pragma unroll
        for (int t = 0; t < 4; t++) acc[t] = (f32x4){0.f, 0.f, 0.f, 0.f};
        #pragma unroll
        for (int ki = 0; ki < 4; ki++)
            #pragma unroll
            for (int t = 0; t < 4; t++)
                acc[t] = __builtin_amdgcn_mfma_f32_16x16x32_bf16(Vf[ki], bf[t][ki], acc[t], 0, 0, 0);
        #pragma unroll
        for (int t = 0; t < 4; t++) {
            const int n = (nt0 + t) * 16 + L15;
            if (n < 128) {
                const float bias = eB[n];
                #pragma unroll
                for (int reg = 0; reg < 4; reg++) {
                    const int tok = tokD0 + reg;
                    e_buf[(size_t)tok * DS + n] = 1.f / (1.f + expf(-(acc[t][reg] + bias)));
                }
            } else {
                const float bias = aB[n - 128];
                #pragma unroll
                for (int reg = 0; reg < 4; reg++) {
                    const int tok = tokD0 + reg;
                    a_buf[(size_t)tok * DS + (n - 128)] = tanhf(acc[t][reg] + bias);
                }
            }
        }
    }

    // ---- GEMM-KM: 12 n-tiles ----
    for (int nt0 = 0; nt0 < 12; nt0 += 4) {
        bfrag bf[4][4];
        #pragma unroll
        for (int t = 0; t < 4; t++)
            #pragma unroll
            for (int ki = 0; ki < 4; ki++)
                bf[t][ki] = Bkm[(size_t)((nt0 + t) * 4 + ki) * 64 + L];
        f32x4 acc[4];
        #pragma unroll
        for (int t = 0; t < 4; t++) acc[t] = (f32x4){0.f, 0.f, 0.f, 0.f};
        #pragma unroll
        for (int ki = 0; ki < 4; ki++)
            #pragma unroll
            for (int t = 0; t < 4; t++)
                acc[t] = __builtin_amdgcn_mfma_f32_16x16x32_bf16(Kf[ki], bf[t][ki], acc[t], 0, 0, 0);
        #pragma unroll
        for (int t = 0; t < 4; t++) {
            const int n = (nt0 + t) * 16 + L15;
            if (n < 128) {
                #pragma unroll
                for (int reg = 0; reg < 4; reg++) {
                    const int tok = tokD0 + reg;
                    kp_buf[(size_t)tok * DS + n] = acc[t][reg];
                }
            } else {
                const int c = n - 128;
                if (c < SM) {
                    #pragma unroll
                    for (int reg = 0; reg < 4; reg++)
                        wl[16 * w + quad * 4 + reg][c] = acc[t][reg];
                }
            }
        }
    }
    __syncthreads();
    if (tid < 64) {
        float mx = -1e30f;
        for (int m = 0; m < SM; m++) mx = fmaxf(mx, wl[tid][m]);
        float sum = 0.f;
        float ex[SM];
        for (int m = 0; m < SM; m++) { ex[m] = expf(wl[tid][m] - mx); sum += ex[m]; }
        const float inv = 1.f / sum;
        float* wp = w_buf + (size_t)(tok0 + tid) * SM;
        for (int m = 0; m < SM; m++) wp[m] = ex[m] * inv;
    }
}

// ---------------- K2: sequential scan (unchanged from R1) ----------------
__global__ __launch_bounds__(64) void k2_scan(
    const float* __restrict__ w_buf, const float* __restrict__ e_buf,
    const float* __restrict__ a_buf, const float* __restrict__ Mv0,
    float* __restrict__ part_buf)
{
    const int bi   = blockIdx.x;
    const int b    = bi / (2*WG);
    const int r    = bi % (2*WG);
    const int dh   = r / WG;
    const int mg   = r % WG;
    const int lane = threadIdx.x;
    const int d    = dh*64 + lane;
    const int m0   = mg * MPG;
    const int base = b * Tn;

    float Mv[MPG];
    #pragma unroll
    for (int m = 0; m < MPG; m++) Mv[m] = Mv0[(size_t)(m0+m)*DS + d];

    float* pout = part_buf + (size_t)mg * NTOK * DS;

    float ev0[4], av0[4], wv0[4][MPG];
    #pragma unroll
    for (int q = 0; q < 4; q++) {
        const int tf = base + q;
        ev0[q] = e_buf[(size_t)tf*DS + d];
        av0[q] = a_buf[(size_t)tf*DS + d];
        #pragma unroll
        for (int m = 0; m < MPG; m++) wv0[q][m] = w_buf[(size_t)tf*SM + m0 + m];
    }

    for (int tb = 0; tb < Tn; tb += 4) {
        float ev1[4] = {}, av1[4] = {}, wv1[4][MPG] = {};
        if (tb + 4 < Tn) {
            #pragma unroll
            for (int q = 0; q < 4; q++) {
                const int tf = base + tb + 4 + q;
                ev1[q] = e_buf[(size_t)tf*DS + d];
                av1[q] = a_buf[(size_t)tf*DS + d];
                #pragma unroll
                for (int m = 0; m < MPG; m++) wv1[q][m] = w_buf[(size_t)tf*SM + m0 + m];
            }
        }
        #pragma unroll
        for (int q = 0; q < 4; q++) {
            float rd = 0.f;
            #pragma unroll
            for (int m = 0; m < MPG; m++) {
                const float wm = wv0[q][m];
                rd = fmaf(wm, Mv[m], rd);
                Mv[m] = fmaf(-wm, fmaf(ev0[q], Mv[m], -av0[q]), Mv[m]);
            }
            pout[(size_t)(base + tb + q)*DS + d] = rd;
        }
        #pragma unroll
        for (int q = 0; q < 4; q++) {
            ev0[q] = ev1[q]; av0[q] = av1[q];
            #pragma unroll
            for (int m = 0; m < MPG; m++) wv0[q][m] = wv1[q][m];
        }
    }
}

// ---------------- K3: combine partials + f-GEMM + pred gather-dot ----------------
__global__ __launch_bounds__(256) void k3_gemm(
    const float* __restrict__ part_buf, const float* __restrict__ kp_buf,
    const unsigned int* __restrict__ Bf0U, const float* __restrict__ fB,
    const float* __restrict__ pW, const float* __restrict__ pB,
    const int* __restrict__ skill, float* __restrict__ out)
{
    const int tid = threadIdx.x;
    const int w = tid >> 6, L = tid & 63, L15 = L & 15, quad = L >> 4;
    const int tok0 = blockIdx.x * 64;
    const int tokA = tok0 + 16 * w + L15;
    const int tokD0 = tok0 + 16 * w + quad * 4;

    // A-frags: reads = sum of the WG scan partials, cast to bf16
    bfrag Rf[4];
    #pragma unroll
    for (int ki = 0; ki < 4; ki++) {
        const float* p0 = part_buf + (size_t)tokA * DS + ki * 32 + quad * 8;
        f32x4 x = (f32x4){0.f,0.f,0.f,0.f}, y = (f32x4){0.f,0.f,0.f,0.f};
        #pragma unroll
        for (int g = 0; g < WG; g++) {
            const f32x4* q = (const f32x4*)(p0 + (size_t)g * NTOK * DS);
            x = x + q[0]; y = y + q[1];
        }
        Rf[ki] = mk_frag(x, y);
    }

    const bfrag* Bf0 = (const bfrag*)Bf0U;
    float f[4][8];   // [reg][nt]

    for (int nt0 = 0; nt0 < 8; nt0 += 4) {
        bfrag bf[4][4];
        #pragma unroll
        for (int t = 0; t < 4; t++)
            #pragma unroll
            for (int ki = 0; ki < 4; ki++)
                bf[t][ki] = Bf0[(size_t)((nt0 + t) * 4 + ki) * 64 + L];
        f32x4 acc[4];
        #pragma unroll
        for (int t = 0; t < 4; t++) acc[t] = (f32x4){0.f, 0.f, 0.f, 0.f};
        #pragma unroll
        for (int ki = 0; ki < 4; ki++)
            #pragma unroll
            for (int t = 0; t < 4; t++)
                acc[t] = __builtin_amdgcn_mfma_f32_16x16x32_bf16(Rf[ki], bf[t][ki], acc[t], 0, 0, 0);
        #pragma unroll
        for (int t = 0; t < 4; t++) {
            const int n = (nt0 + t) * 16 + L15;
            const float fb = fB[n];
            #pragma unroll
            for (int reg = 0; reg < 4; reg++) {
                const int tok = tokD0 + reg;
                f[reg][nt0 + t] = tanhf(acc[t][reg] + kp_buf[(size_t)tok * DS + n] + fb);
            }
        }
    }

    // pred: per D-row token, dot(f, pW[ix]) reduced over the 16 lanes (L15)
    #pragma unroll
    for (int reg = 0; reg < 4; reg++) {
        const int tok = tokD0 + reg;
        const int t = tok % Tn;
        const bool act = (t < Tn - 1);
        int sn = 0, ix = 0;
        float contrib = 0.f;
        if (act) {
            sn = skill[tok + 1];
            ix = (sn < NUMC) ? sn : (NUMC - 1);
            const float* pr = pW + (size_t)ix * DS + L15;
            #pragma unroll
            for (int nt = 0; nt < 8; nt++)
                contrib = fmaf(f[reg][nt], pr[nt * 16], contrib);
        }
        #pragma unroll
        for (int msk = 1; msk <= 8; msk <<= 1)
            contrib += __shfl_xor(contrib, msk);
        if (act && L15 == 0) {
            const float val = contrib + pB[ix];
            const float prd = (sn < NUMC) ? (1.f / (1.f + expf(-val))) : 0.f;
            out[(size_t)(tok / Tn) * (Tn - 1) + t] = prd;
        }
    }
}

extern "C" void kernel_launch(void* const* d_in, const int* in_sizes, int n_in,
                              void* d_out, int out_size, void* d_ws, size_t ws_size,
                              hipStream_t stream)
{
    const int*   skill  = (const int*)  d_in[0];
    const int*   answer = (const int*)  d_in[1];
    const float* k_emb  = (const float*)d_in[2];
    const float* v_emb  = (const float*)d_in[3];
    const float* Mk     = (const float*)d_in[4];
    const float* Mv0    = (const float*)d_in[5];
    const float* f_W    = (const float*)d_in[6];
    const float* f_b    = (const float*)d_in[7];
    const float* p_W    = (const float*)d_in[8];
    const float* p_b    = (const float*)d_in[9];
    const float* e_W    = (const float*)d_in[10];
    const float* e_b    = (const float*)d_in[11];
    const float* a_W    = (const float*)d_in[12];
    const float* a_b    = (const float*)d_in[13];
    float* out = (float*)d_out;

    float* ws       = (float*)d_ws;
    float* w_buf    = ws;                                  // NTOK*SM
    float* e_buf    = w_buf    + (size_t)NTOK*SM;
    float* a_buf    = e_buf    + (size_t)NTOK*DS;
    float* kp_buf   = a_buf    + (size_t)NTOK*DS;
    float* part_buf = kp_buf   + (size_t)NTOK*DS;          // WG*NTOK*DS
    unsigned int* BeaU = (unsigned int*)(part_buf + (size_t)WG*NTOK*DS);
    unsigned int* BkmU = BeaU + 4096 * 4;   // 4096 groups * 16B
    unsigned int* Bf0U = BkmU + 3072 * 4;
    // total ~55.1 MB of d_ws

    k0_cast<<<36, 256, 0, stream>>>(e_W, a_W, f_W, Mk, BeaU, BkmU, Bf0U);
    k1_gemm<<<NTOK/64, 256, 0, stream>>>(skill, answer, k_emb, v_emb,
        BeaU, BkmU, e_b, a_b, w_buf, e_buf, a_buf, kp_buf);
    k2_scan<<<Bsz*2*WG, 64, 0, stream>>>(w_buf, e_buf, a_buf, Mv0, part_buf);
    k3_gemm<<<NTOK/64, 256, 0, stream>>>(part_buf, kp_buf, Bf0U, f_b,
        p_W, p_b, skill, out);
}

// Round 3
// 156.452 us; speedup vs baseline: 1.6738x; 1.0599x over previous
//
#include <hip/hip_runtime.h>
#include <math.h>

#define Bsz 64
#define Tn 200
#define NUMC 2000
#define DS 128
#define SM 50
#define NTOK (Bsz*Tn)
#define WG2 10       // m-groups in scan
#define MPG2 5       // m per group (WG2*MPG2 == SM)

typedef __attribute__((ext_vector_type(8))) short bfrag;
typedef __attribute__((ext_vector_type(4))) float f32x4;
typedef __attribute__((ext_vector_type(4))) unsigned int u32x4;

__device__ __forceinline__ unsigned short f2bf(float x) {
    unsigned int u = __builtin_bit_cast(unsigned int, x);
    u = u + 0x7fffu + ((u >> 16) & 1u);   // RNE
    return (unsigned short)(u >> 16);
}
__device__ __forceinline__ unsigned int pack2(float a, float b) {
    return (unsigned int)f2bf(a) | ((unsigned int)f2bf(b) << 16);
}
__device__ __forceinline__ bfrag mk_frag(f32x4 x, f32x4 y) {
    u32x4 t;
    t[0] = pack2(x[0], x[1]); t[1] = pack2(x[2], x[3]);
    t[2] = pack2(y[0], y[1]); t[3] = pack2(y[2], y[3]);
    return __builtin_bit_cast(bfrag, t);
}

__device__ __forceinline__ void load_group(const bfrag* __restrict__ B, int nt0, int L, bfrag bf[4][4]) {
    #pragma unroll
    for (int t = 0; t < 4; t++)
        #pragma unroll
        for (int ki = 0; ki < 4; ki++)
            bf[t][ki] = B[(size_t)((nt0 + t) * 4 + ki) * 64 + L];
}
__device__ __forceinline__ void mfma_group(const bfrag A[4], const bfrag bf[4][4], f32x4 acc[4]) {
    #pragma unroll
    for (int ki = 0; ki < 4; ki++)
        #pragma unroll
        for (int t = 0; t < 4; t++)
            acc[t] = __builtin_amdgcn_mfma_f32_16x16x32_bf16(A[ki], bf[t][ki], acc[t], 0, 0, 0);
}

// ---------------- K0: cast weights into MFMA b-frag block layout ----------------
// lane L holds W[n = nt*16 + (L&15)][k = ki*32 + (L>>4)*8 + j], j=0..7.
// Bea: rows 0-127 = e_W, 128-255 = a_W          (16 n-tiles)
// Bkm: rows 0-127 = f_W[:,128:256], 128-177 = Mk, 178-191 = 0   (12 n-tiles)
// Bf0: rows 0-127 = f_W[:,0:128]                (8 n-tiles)
__global__ __launch_bounds__(256) void k0_cast(
    const float* __restrict__ eW, const float* __restrict__ aW,
    const float* __restrict__ fW, const float* __restrict__ Mk,
    unsigned int* __restrict__ BeaU, unsigned int* __restrict__ BkmU,
    unsigned int* __restrict__ Bf0U)
{
    const int g = blockIdx.x * 256 + threadIdx.x;
    if (g >= 9216) return;
    int gm, mat;
    unsigned int* dst;
    if (g < 4096)      { mat = 0; gm = g;        dst = BeaU; }
    else if (g < 7168) { mat = 1; gm = g - 4096; dst = BkmU; }
    else               { mat = 2; gm = g - 7168; dst = Bf0U; }
    const int nt = gm >> 8, r = gm & 255, ki = r >> 6, L = r & 63;
    const int n = nt * 16 + (L & 15);
    const int k = ki * 32 + (L >> 4) * 8;

    const float* src = nullptr;
    if (mat == 0) {
        src = (n < 128) ? (eW + (size_t)n * DS + k) : (aW + (size_t)(n - 128) * DS + k);
    } else if (mat == 1) {
        if (n < 128)      src = fW + (size_t)n * (2 * DS) + DS + k;
        else if (n < 128 + SM) src = Mk + (size_t)(n - 128) * DS + k;
    } else {
        src = fW + (size_t)n * (2 * DS) + k;
    }
    float v[8];
    #pragma unroll
    for (int j = 0; j < 8; j++) v[j] = src ? src[j] : 0.f;
    u32x4 o;
    o[0] = pack2(v[0], v[1]); o[1] = pack2(v[2], v[3]);
    o[2] = pack2(v[4], v[5]); o[3] = pack2(v[6], v[7]);
    ((u32x4*)dst)[gm] = o;
}

// ---------------- K1: gather + two bf16 MFMA GEMMs + softmax ----------------
__global__ __launch_bounds__(256) void k1_gemm(
    const int* __restrict__ skill, const int* __restrict__ answer,
    const float* __restrict__ k_emb, const float* __restrict__ v_emb,
    const unsigned int* __restrict__ BeaU, const unsigned int* __restrict__ BkmU,
    const float* __restrict__ eB, const float* __restrict__ aB,
    float* __restrict__ w_buf, float* __restrict__ e_buf,
    float* __restrict__ a_buf, float* __restrict__ kp_buf)
{
    const int tid = threadIdx.x;
    const int w = tid >> 6, L = tid & 63, L15 = L & 15, quad = L >> 4;
    const int tok0 = blockIdx.x * 64;
    const int tokA = tok0 + 16 * w + L15;
    const int tokD0 = tok0 + 16 * w + quad * 4;

    const int s  = skill[tokA];
    const int an = answer[tokA];
    const int ax = (an == 2) ? 1 : an;
    const float* vp = v_emb + ((size_t)(s + NUMC * ax)) * DS + quad * 8;
    const float* kp = k_emb + (size_t)s * DS + quad * 8;

    bfrag Vf[4], Kf[4];
    #pragma unroll
    for (int ki = 0; ki < 4; ki++) {
        const f32x4* a = (const f32x4*)(vp + ki * 32);
        Vf[ki] = mk_frag(a[0], a[1]);
        const f32x4* b = (const f32x4*)(kp + ki * 32);
        Kf[ki] = mk_frag(b[0], b[1]);
    }

    const bfrag* Bea = (const bfrag*)BeaU;
    const bfrag* Bkm = (const bfrag*)BkmU;

    __shared__ float wl[64][52];

    // ---- GEMM-EA: tiles 0-7 -> e (sigmoid), tiles 8-15 -> a (tanh); ping-pong B prefetch ----
    {
        bfrag bfA[4][4], bfB[4][4];
        load_group(Bea, 0, L, bfA);
        load_group(Bea, 4, L, bfB);

        #define EA_EPI_E(NT0, ACC)                                              \
            { _Pragma("unroll")                                                 \
              for (int t = 0; t < 4; t++) {                                     \
                const int n = (NT0 + t) * 16 + L15;                             \
                const float bias = eB[n];                                       \
                _Pragma("unroll")                                               \
                for (int reg = 0; reg < 4; reg++)                               \
                    e_buf[(size_t)(tokD0 + reg) * DS + n] =                     \
                        1.f / (1.f + expf(-(ACC[t][reg] + bias)));              \
              } }
        #define EA_EPI_A(NT0, ACC)                                              \
            { _Pragma("unroll")                                                 \
              for (int t = 0; t < 4; t++) {                                     \
                const int n = (NT0 + t) * 16 + L15 - 128;                       \
                const float bias = aB[n];                                       \
                _Pragma("unroll")                                               \
                for (int reg = 0; reg < 4; reg++)                               \
                    a_buf[(size_t)(tokD0 + reg) * DS + n] =                     \
                        tanhf(ACC[t][reg] + bias);                              \
              } }

        f32x4 acc[4];
        #pragma unroll
        for (int t = 0; t < 4; t++) acc[t] = (f32x4){0.f,0.f,0.f,0.f};
        mfma_group(Vf, bfA, acc);
        load_group(Bea, 8, L, bfA);
        EA_EPI_E(0, acc);

        #pragma unroll
        for (int t = 0; t < 4; t++) acc[t] = (f32x4){0.f,0.f,0.f,0.f};
        mfma_group(Vf, bfB, acc);
        load_group(Bea, 12, L, bfB);
        EA_EPI_E(4, acc);

        #pragma unroll
        for (int t = 0; t < 4; t++) acc[t] = (f32x4){0.f,0.f,0.f,0.f};
        mfma_group(Vf, bfA, acc);
        EA_EPI_A(8, acc);

        #pragma unroll
        for (int t = 0; t < 4; t++) acc[t] = (f32x4){0.f,0.f,0.f,0.f};
        mfma_group(Vf, bfB, acc);
        EA_EPI_A(12, acc);
    }

    // ---- GEMM-KM: tiles 0-7 -> kpart, tiles 8-11 -> w logits ----
    {
        bfrag bfA[4][4], bfB[4][4];
        load_group(Bkm, 0, L, bfA);
        load_group(Bkm, 4, L, bfB);

        f32x4 acc[4];
        #pragma unroll
        for (int t = 0; t < 4; t++) acc[t] = (f32x4){0.f,0.f,0.f,0.f};
        mfma_group(Kf, bfA, acc);
        load_group(Bkm, 8, L, bfA);
        #pragma unroll
        for (int t = 0; t < 4; t++) {
            const int n = t * 16 + L15;
            #pragma unroll
            for (int reg = 0; reg < 4; reg++)
                kp_buf[(size_t)(tokD0 + reg) * DS + n] = acc[t][reg];
        }

        #pragma unroll
        for (int t = 0; t < 4; t++) acc[t] = (f32x4){0.f,0.f,0.f,0.f};
        mfma_group(Kf, bfB, acc);
        #pragma unroll
        for (int t = 0; t < 4; t++) {
            const int n = (4 + t) * 16 + L15;
            #pragma unroll
            for (int reg = 0; reg < 4; reg++)
                kp_buf[(size_t)(tokD0 + reg) * DS + n] = acc[t][reg];
        }

        #pragma unroll
        for (int t = 0; t < 4; t++) acc[t] = (f32x4){0.f,0.f,0.f,0.f};
        mfma_group(Kf, bfA, acc);
        #pragma unroll
        for (int t = 0; t < 4; t++) {
            const int c = (8 + t) * 16 + L15 - 128;
            if (c < SM) {
                #pragma unroll
                for (int reg = 0; reg < 4; reg++)
                    wl[16 * w + quad * 4 + reg][c] = acc[t][reg];
            }
        }
    }
    __syncthreads();
    if (tid < 64) {
        float mx = -1e30f;
        for (int m = 0; m < SM; m++) mx = fmaxf(mx, wl[tid][m]);
        float sum = 0.f;
        float ex[SM];
        for (int m = 0; m < SM; m++) { ex[m] = expf(wl[tid][m] - mx); sum += ex[m]; }
        const float inv = 1.f / sum;
        float* wp = w_buf + (size_t)(tok0 + tid) * SM;
        for (int m = 0; m < SM; m++) wp[m] = ex[m] * inv;
    }
}

// ---------------- K2: scan; (b, d-half, m-group) waves; 4-stage register ring ----------------
__global__ __launch_bounds__(64) void k2_scan(
    const float* __restrict__ w_buf, const float* __restrict__ e_buf,
    const float* __restrict__ a_buf, const float* __restrict__ Mv0,
    float* __restrict__ part_buf)
{
    const int bi   = blockIdx.x;
    const int b    = bi / (2*WG2);
    const int r    = bi % (2*WG2);
    const int dh   = r / WG2;
    const int mg   = r % WG2;
    const int lane = threadIdx.x;
    const int d    = dh*64 + lane;
    const int m0   = mg * MPG2;
    const int base = b * Tn;

    float Mv[MPG2];
    #pragma unroll
    for (int m = 0; m < MPG2; m++) Mv[m] = Mv0[(size_t)(m0+m)*DS + d];

    float* pout = part_buf + (size_t)mg * NTOK * DS;

    // 4 stages x 2 timesteps: 8 timesteps in flight
    float se[4][2], sa[4][2], sw[4][2][MPG2];

    #define LOADST(ST, T)                                                      \
        { const int tc_ = ((T) < Tn) ? (T) : 0;                                \
          _Pragma("unroll")                                                    \
          for (int q_ = 0; q_ < 2; q_++) {                                     \
              const int tf_ = base + tc_ + q_;                                 \
              se[ST][q_] = e_buf[(size_t)tf_*DS + d];                          \
              sa[ST][q_] = a_buf[(size_t)tf_*DS + d];                          \
              _Pragma("unroll")                                                \
              for (int m_ = 0; m_ < MPG2; m_++)                                \
                  sw[ST][q_][m_] = w_buf[(size_t)tf_*SM + m0 + m_];            \
          } }

    LOADST(0, 0) LOADST(1, 2) LOADST(2, 4) LOADST(3, 6)

    for (int i = 0; i < 25; i++) {
        const int tb = i * 8;
        #pragma unroll
        for (int sub = 0; sub < 4; sub++) {
            const int t0 = tb + sub * 2;
            #pragma unroll
            for (int q = 0; q < 2; q++) {
                const float ev = se[sub][q], av = sa[sub][q];
                float rd = 0.f;
                #pragma unroll
                for (int m = 0; m < MPG2; m++) {
                    const float wm = sw[sub][q][m];
                    rd = fmaf(wm, Mv[m], rd);                               // read uses OLD Mv
                    Mv[m] = fmaf(-wm, fmaf(ev, Mv[m], -av), Mv[m]);         // Mv*(1-w*e)+w*a
                }
                pout[(size_t)(base + t0 + q)*DS + d] = rd;
            }
            LOADST(sub, t0 + 8)
        }
    }
}

// ---------------- K3: combine partials + f-GEMM + pred gather-dot ----------------
__global__ __launch_bounds__(256) void k3_gemm(
    const float* __restrict__ part_buf, const float* __restrict__ kp_buf,
    const unsigned int* __restrict__ Bf0U, const float* __restrict__ fB,
    const float* __restrict__ pW, const float* __restrict__ pB,
    const int* __restrict__ skill, float* __restrict__ out)
{
    const int tid = threadIdx.x;
    const int w = tid >> 6, L = tid & 63, L15 = L & 15, quad = L >> 4;
    const int tok0 = blockIdx.x * 64;
    const int tokA = tok0 + 16 * w + L15;
    const int tokD0 = tok0 + 16 * w + quad * 4;

    const bfrag* Bf0 = (const bfrag*)Bf0U;
    bfrag bfA[4][4], bfB[4][4];
    load_group(Bf0, 0, L, bfA);
    load_group(Bf0, 4, L, bfB);

    // A-frags: reads = sum of the WG2 scan partials, cast to bf16
    bfrag Rf[4];
    #pragma unroll
    for (int ki = 0; ki < 4; ki++) {
        const float* p0 = part_buf + (size_t)tokA * DS + ki * 32 + quad * 8;
        f32x4 x = (f32x4){0.f,0.f,0.f,0.f}, y = (f32x4){0.f,0.f,0.f,0.f};
        #pragma unroll
        for (int g = 0; g < WG2; g++) {
            const f32x4* q4 = (const f32x4*)(p0 + (size_t)g * NTOK * DS);
            x = x + q4[0]; y = y + q4[1];
        }
        Rf[ki] = mk_frag(x, y);
    }

    float f[4][8];   // [reg][nt]
    f32x4 acc[4];

    #pragma unroll
    for (int t = 0; t < 4; t++) acc[t] = (f32x4){0.f,0.f,0.f,0.f};
    mfma_group(Rf, bfA, acc);
    #pragma unroll
    for (int t = 0; t < 4; t++) {
        const int n = t * 16 + L15;
        const float fb = fB[n];
        #pragma unroll
        for (int reg = 0; reg < 4; reg++)
            f[reg][t] = tanhf(acc[t][reg] + kp_buf[(size_t)(tokD0 + reg) * DS + n] + fb);
    }

    #pragma unroll
    for (int t = 0; t < 4; t++) acc[t] = (f32x4){0.f,0.f,0.f,0.f};
    mfma_group(Rf, bfB, acc);
    #pragma unroll
    for (int t = 0; t < 4; t++) {
        const int n = (4 + t) * 16 + L15;
        const float fb = fB[n];
        #pragma unroll
        for (int reg = 0; reg < 4; reg++)
            f[reg][4 + t] = tanhf(acc[t][reg] + kp_buf[(size_t)(tokD0 + reg) * DS + n] + fb);
    }

    // pred: per D-row token, dot(f, pW[ix]) reduced over the 16 lanes (L15)
    #pragma unroll
    for (int reg = 0; reg < 4; reg++) {
        const int tok = tokD0 + reg;
        const int t = tok % Tn;
        const bool act = (t < Tn - 1);
        int sn = 0, ix = 0;
        float contrib = 0.f;
        if (act) {
            sn = skill[tok + 1];
            ix = (sn < NUMC) ? sn : (NUMC - 1);
            const float* pr = pW + (size_t)ix * DS + L15;
            #pragma unroll
            for (int nt = 0; nt < 8; nt++)
                contrib = fmaf(f[reg][nt], pr[nt * 16], contrib);
        }
        #pragma unroll
        for (int msk = 1; msk <= 8; msk <<= 1)
            contrib += __shfl_xor(contrib, msk);
        if (act && L15 == 0) {
            const float val = contrib + pB[ix];
            const float prd = (sn < NUMC) ? (1.f / (1.f + expf(-val))) : 0.f;
            out[(size_t)(tok / Tn) * (Tn - 1) + t] = prd;
        }
    }
}

extern "C" void kernel_launch(void* const* d_in, const int* in_sizes, int n_in,
                              void* d_out, int out_size, void* d_ws, size_t ws_size,
                              hipStream_t stream)
{
    const int*   skill  = (const int*)  d_in[0];
    const int*   answer = (const int*)  d_in[1];
    const float* k_emb  = (const float*)d_in[2];
    const float* v_emb  = (const float*)d_in[3];
    const float* Mk     = (const float*)d_in[4];
    const float* Mv0    = (const float*)d_in[5];
    const float* f_W    = (const float*)d_in[6];
    const float* f_b    = (const float*)d_in[7];
    const float* p_W    = (const float*)d_in[8];
    const float* p_b    = (const float*)d_in[9];
    const float* e_W    = (const float*)d_in[10];
    const float* e_b    = (const float*)d_in[11];
    const float* a_W    = (const float*)d_in[12];
    const float* a_b    = (const float*)d_in[13];
    float* out = (float*)d_out;

    float* ws       = (float*)d_ws;
    float* w_buf    = ws;                                  // NTOK*SM
    float* e_buf    = w_buf    + (size_t)NTOK*SM;
    float* a_buf    = e_buf    + (size_t)NTOK*DS;
    float* kp_buf   = a_buf    + (size_t)NTOK*DS;
    float* part_buf = kp_buf   + (size_t)NTOK*DS;          // WG2*NTOK*DS
    unsigned int* BeaU = (unsigned int*)(part_buf + (size_t)WG2*NTOK*DS);
    unsigned int* BkmU = BeaU + 4096 * 4;
    unsigned int* Bf0U = BkmU + 3072 * 4;
    // total ~93 MB of d_ws

    k0_cast<<<36, 256, 0, stream>>>(e_W, a_W, f_W, Mk, BeaU, BkmU, Bf0U);
    k1_gemm<<<NTOK/64, 256, 0, stream>>>(skill, answer, k_emb, v_emb,
        BeaU, BkmU, e_b, a_b, w_buf, e_buf, a_buf, kp_buf);
    k2_scan<<<Bsz*2*WG2, 64, 0, stream>>>(w_buf, e_buf, a_buf, Mv0, part_buf);
    k3_gemm<<<NTOK/64, 256, 0, stream>>>(part_buf, kp_buf, Bf0U, f_b,
        p_W, p_b, skill, out);
}

// Round 4
// 140.604 us; speedup vs baseline: 1.8625x; 1.1127x over previous
//
#include <hip/hip_runtime.h>
#include <math.h>

#define Bsz 64
#define Tn 200
#define NUMC 2000
#define DS 128
#define SM 50
#define NTOK (Bsz*Tn)
#define WG2 10       // m-groups in scan
#define MPG2 5       // m per group (WG2*MPG2 == SM)

typedef __attribute__((ext_vector_type(8))) short bfrag;
typedef __attribute__((ext_vector_type(4))) float f32x4;
typedef __attribute__((ext_vector_type(4))) unsigned int u32x4;

__device__ __forceinline__ unsigned short f2bf(float x) {
    unsigned int u = __builtin_bit_cast(unsigned int, x);
    u = u + 0x7fffu + ((u >> 16) & 1u);   // RNE
    return (unsigned short)(u >> 16);
}
__device__ __forceinline__ unsigned int pack2(float a, float b) {
    return (unsigned int)f2bf(a) | ((unsigned int)f2bf(b) << 16);
}
__device__ __forceinline__ bfrag mk_frag(f32x4 x, f32x4 y) {
    u32x4 t;
    t[0] = pack2(x[0], x[1]); t[1] = pack2(x[2], x[3]);
    t[2] = pack2(y[0], y[1]); t[3] = pack2(y[2], y[3]);
    return __builtin_bit_cast(bfrag, t);
}

// fast transcendentals: v_exp_f32 / v_rcp_f32 (~1e-6 rel err, invisible at bf16 grade)
__device__ __forceinline__ float fast_exp(float x)  { return __builtin_amdgcn_exp2f(x * 1.44269504f); }
__device__ __forceinline__ float fast_rcp(float x)  { return __builtin_amdgcn_rcpf(x); }
__device__ __forceinline__ float fast_sigmoid(float x) { return fast_rcp(1.f + fast_exp(-x)); }
__device__ __forceinline__ float fast_tanh(float x) { return 1.f - 2.f * fast_rcp(fast_exp(2.f * x) + 1.f); }

__device__ __forceinline__ void load_group(const bfrag* __restrict__ B, int nt0, int L, bfrag bf[4][4]) {
    #pragma unroll
    for (int t = 0; t < 4; t++)
        #pragma unroll
        for (int ki = 0; ki < 4; ki++)
            bf[t][ki] = B[(size_t)((nt0 + t) * 4 + ki) * 64 + L];
}
__device__ __forceinline__ void mfma_group(const bfrag A[4], const bfrag bf[4][4], f32x4 acc[4]) {
    #pragma unroll
    for (int ki = 0; ki < 4; ki++)
        #pragma unroll
        for (int t = 0; t < 4; t++)
            acc[t] = __builtin_amdgcn_mfma_f32_16x16x32_bf16(A[ki], bf[t][ki], acc[t], 0, 0, 0);
}

// ---------------- K0: cast weights into MFMA b-frag block layout ----------------
// lane L holds W[n = nt*16 + (L&15)][k = ki*32 + (L>>4)*8 + j], j=0..7.
// Bea: rows 0-127 = e_W, 128-255 = a_W          (16 n-tiles)
// Bkm: rows 0-127 = f_W[:,128:256], 128-177 = Mk, 178-191 = 0   (12 n-tiles)
// Bf0: rows 0-127 = f_W[:,0:128]                (8 n-tiles)
__global__ __launch_bounds__(256) void k0_cast(
    const float* __restrict__ eW, const float* __restrict__ aW,
    const float* __restrict__ fW, const float* __restrict__ Mk,
    unsigned int* __restrict__ BeaU, unsigned int* __restrict__ BkmU,
    unsigned int* __restrict__ Bf0U)
{
    const int g = blockIdx.x * 256 + threadIdx.x;
    if (g >= 9216) return;
    int gm, mat;
    unsigned int* dst;
    if (g < 4096)      { mat = 0; gm = g;        dst = BeaU; }
    else if (g < 7168) { mat = 1; gm = g - 4096; dst = BkmU; }
    else               { mat = 2; gm = g - 7168; dst = Bf0U; }
    const int nt = gm >> 8, r = gm & 255, ki = r >> 6, L = r & 63;
    const int n = nt * 16 + (L & 15);
    const int k = ki * 32 + (L >> 4) * 8;

    const float* src = nullptr;
    if (mat == 0) {
        src = (n < 128) ? (eW + (size_t)n * DS + k) : (aW + (size_t)(n - 128) * DS + k);
    } else if (mat == 1) {
        if (n < 128)      src = fW + (size_t)n * (2 * DS) + DS + k;
        else if (n < 128 + SM) src = Mk + (size_t)(n - 128) * DS + k;
    } else {
        src = fW + (size_t)n * (2 * DS) + k;
    }
    float v[8];
    #pragma unroll
    for (int j = 0; j < 8; j++) v[j] = src ? src[j] : 0.f;
    u32x4 o;
    o[0] = pack2(v[0], v[1]); o[1] = pack2(v[2], v[3]);
    o[2] = pack2(v[4], v[5]); o[3] = pack2(v[6], v[7]);
    ((u32x4*)dst)[gm] = o;
}

// ---------------- K1: 1-wave blocks; bid<800 -> EA wave, else KM wave ----------------
__global__ __launch_bounds__(64) void k1_gemm(
    const int* __restrict__ skill, const int* __restrict__ answer,
    const float* __restrict__ k_emb, const float* __restrict__ v_emb,
    const unsigned int* __restrict__ BeaU, const unsigned int* __restrict__ BkmU,
    const float* __restrict__ eB, const float* __restrict__ aB,
    float* __restrict__ w_buf, float* __restrict__ e_buf,
    float* __restrict__ a_buf, float* __restrict__ kp_buf)
{
    const int bid = blockIdx.x;
    const int L = threadIdx.x, L15 = L & 15, quad = L >> 4;

    if (bid < NTOK/16) {
        // ===== EA wave: V @ Bea^T -> e (tiles 0-7, sigmoid), a (tiles 8-15, tanh) =====
        const int tok0 = bid * 16;
        const int tokA = tok0 + L15;
        const int tokD0 = tok0 + quad * 4;

        const bfrag* Bea = (const bfrag*)BeaU;
        bfrag bfA[4][4], bfB[4][4];
        load_group(Bea, 0, L, bfA);
        load_group(Bea, 4, L, bfB);

        const int s  = skill[tokA];
        const int an = answer[tokA];
        const int ax = (an == 2) ? 1 : an;
        const float* vp = v_emb + ((size_t)(s + NUMC * ax)) * DS + quad * 8;
        bfrag Vf[4];
        #pragma unroll
        for (int ki = 0; ki < 4; ki++) {
            const f32x4* a = (const f32x4*)(vp + ki * 32);
            Vf[ki] = mk_frag(a[0], a[1]);
        }

        f32x4 acc[4];
        #pragma unroll
        for (int t = 0; t < 4; t++) acc[t] = (f32x4){0.f,0.f,0.f,0.f};
        mfma_group(Vf, bfA, acc);
        load_group(Bea, 8, L, bfA);
        #pragma unroll
        for (int t = 0; t < 4; t++) {
            const int n = t * 16 + L15;
            const float bias = eB[n];
            #pragma unroll
            for (int reg = 0; reg < 4; reg++)
                e_buf[(size_t)(tokD0 + reg) * DS + n] = fast_sigmoid(acc[t][reg] + bias);
        }

        #pragma unroll
        for (int t = 0; t < 4; t++) acc[t] = (f32x4){0.f,0.f,0.f,0.f};
        mfma_group(Vf, bfB, acc);
        load_group(Bea, 12, L, bfB);
        #pragma unroll
        for (int t = 0; t < 4; t++) {
            const int n = (4 + t) * 16 + L15;
            const float bias = eB[n];
            #pragma unroll
            for (int reg = 0; reg < 4; reg++)
                e_buf[(size_t)(tokD0 + reg) * DS + n] = fast_sigmoid(acc[t][reg] + bias);
        }

        #pragma unroll
        for (int t = 0; t < 4; t++) acc[t] = (f32x4){0.f,0.f,0.f,0.f};
        mfma_group(Vf, bfA, acc);
        #pragma unroll
        for (int t = 0; t < 4; t++) {
            const int n = t * 16 + L15;
            const float bias = aB[n];
            #pragma unroll
            for (int reg = 0; reg < 4; reg++)
                a_buf[(size_t)(tokD0 + reg) * DS + n] = fast_tanh(acc[t][reg] + bias);
        }

        #pragma unroll
        for (int t = 0; t < 4; t++) acc[t] = (f32x4){0.f,0.f,0.f,0.f};
        mfma_group(Vf, bfB, acc);
        #pragma unroll
        for (int t = 0; t < 4; t++) {
            const int n = (4 + t) * 16 + L15;
            const float bias = aB[n];
            #pragma unroll
            for (int reg = 0; reg < 4; reg++)
                a_buf[(size_t)(tokD0 + reg) * DS + n] = fast_tanh(acc[t][reg] + bias);
        }
    } else {
        // ===== KM wave: K @ Bkm^T -> kpart (tiles 0-7), w logits (tiles 8-11) + softmax =====
        const int tok0 = (bid - NTOK/16) * 16;
        const int tokA = tok0 + L15;
        const int tokD0 = tok0 + quad * 4;

        const bfrag* Bkm = (const bfrag*)BkmU;
        bfrag bfA[4][4], bfB[4][4];
        load_group(Bkm, 0, L, bfA);
        load_group(Bkm, 4, L, bfB);

        const int s = skill[tokA];
        const float* kp = k_emb + (size_t)s * DS + quad * 8;
        bfrag Kf[4];
        #pragma unroll
        for (int ki = 0; ki < 4; ki++) {
            const f32x4* b = (const f32x4*)(kp + ki * 32);
            Kf[ki] = mk_frag(b[0], b[1]);
        }

        __shared__ float wl[16][52];

        f32x4 acc[4];
        #pragma unroll
        for (int t = 0; t < 4; t++) acc[t] = (f32x4){0.f,0.f,0.f,0.f};
        mfma_group(Kf, bfA, acc);
        load_group(Bkm, 8, L, bfA);
        #pragma unroll
        for (int t = 0; t < 4; t++) {
            const int n = t * 16 + L15;
            #pragma unroll
            for (int reg = 0; reg < 4; reg++)
                kp_buf[(size_t)(tokD0 + reg) * DS + n] = acc[t][reg];
        }

        #pragma unroll
        for (int t = 0; t < 4; t++) acc[t] = (f32x4){0.f,0.f,0.f,0.f};
        mfma_group(Kf, bfB, acc);
        #pragma unroll
        for (int t = 0; t < 4; t++) {
            const int n = (4 + t) * 16 + L15;
            #pragma unroll
            for (int reg = 0; reg < 4; reg++)
                kp_buf[(size_t)(tokD0 + reg) * DS + n] = acc[t][reg];
        }

        #pragma unroll
        for (int t = 0; t < 4; t++) acc[t] = (f32x4){0.f,0.f,0.f,0.f};
        mfma_group(Kf, bfA, acc);
        #pragma unroll
        for (int t = 0; t < 4; t++) {
            const int c = (8 + t) * 16 + L15 - 128;
            if (c < SM) {
                #pragma unroll
                for (int reg = 0; reg < 4; reg++)
                    wl[quad * 4 + reg][c] = acc[t][reg];
            }
        }
        __syncthreads();
        if (L < 16) {
            float mx = -1e30f;
            for (int m = 0; m < SM; m++) mx = fmaxf(mx, wl[L][m]);
            float sum = 0.f;
            float ex[SM];
            for (int m = 0; m < SM; m++) { ex[m] = fast_exp(wl[L][m] - mx); sum += ex[m]; }
            const float inv = fast_rcp(sum);
            float* wp = w_buf + (size_t)(tok0 + L) * SM;
            for (int m = 0; m < SM; m++) wp[m] = ex[m] * inv;
        }
    }
}

// ---------------- K2: scan; (b, d-half, m-group) waves; 4-stage register ring ----------------
__global__ __launch_bounds__(64) void k2_scan(
    const float* __restrict__ w_buf, const float* __restrict__ e_buf,
    const float* __restrict__ a_buf, const float* __restrict__ Mv0,
    float* __restrict__ part_buf)
{
    const int bi   = blockIdx.x;
    const int b    = bi / (2*WG2);
    const int r    = bi % (2*WG2);
    const int dh   = r / WG2;
    const int mg   = r % WG2;
    const int lane = threadIdx.x;
    const int d    = dh*64 + lane;
    const int m0   = mg * MPG2;
    const int base = b * Tn;

    float Mv[MPG2];
    #pragma unroll
    for (int m = 0; m < MPG2; m++) Mv[m] = Mv0[(size_t)(m0+m)*DS + d];

    float* pout = part_buf + (size_t)mg * NTOK * DS;

    float se[4][2], sa[4][2], sw[4][2][MPG2];

    #define LOADST(ST, T)                                                      \
        { const int tc_ = ((T) < Tn) ? (T) : 0;                                \
          _Pragma("unroll")                                                    \
          for (int q_ = 0; q_ < 2; q_++) {                                     \
              const int tf_ = base + tc_ + q_;                                 \
              se[ST][q_] = e_buf[(size_t)tf_*DS + d];                          \
              sa[ST][q_] = a_buf[(size_t)tf_*DS + d];                          \
              _Pragma("unroll")                                                \
              for (int m_ = 0; m_ < MPG2; m_++)                                \
                  sw[ST][q_][m_] = w_buf[(size_t)tf_*SM + m0 + m_];            \
          } }

    LOADST(0, 0) LOADST(1, 2) LOADST(2, 4) LOADST(3, 6)

    for (int i = 0; i < 25; i++) {
        const int tb = i * 8;
        #pragma unroll
        for (int sub = 0; sub < 4; sub++) {
            const int t0 = tb + sub * 2;
            #pragma unroll
            for (int q = 0; q < 2; q++) {
                const float ev = se[sub][q], av = sa[sub][q];
                float rd = 0.f;
                #pragma unroll
                for (int m = 0; m < MPG2; m++) {
                    const float wm = sw[sub][q][m];
                    rd = fmaf(wm, Mv[m], rd);                               // read uses OLD Mv
                    Mv[m] = fmaf(-wm, fmaf(ev, Mv[m], -av), Mv[m]);         // Mv*(1-w*e)+w*a
                }
                pout[(size_t)(base + t0 + q)*DS + d] = rd;
            }
            LOADST(sub, t0 + 8)
        }
    }
}

// ---------------- K3: 1-wave blocks; combine partials + f-GEMM + pred gather-dot ----------------
__global__ __launch_bounds__(64) void k3_gemm(
    const float* __restrict__ part_buf, const float* __restrict__ kp_buf,
    const unsigned int* __restrict__ Bf0U, const float* __restrict__ fB,
    const float* __restrict__ pW, const float* __restrict__ pB,
    const int* __restrict__ skill, float* __restrict__ out)
{
    const int L = threadIdx.x, L15 = L & 15, quad = L >> 4;
    const int tok0 = blockIdx.x * 16;
    const int tokA = tok0 + L15;
    const int tokD0 = tok0 + quad * 4;

    const bfrag* Bf0 = (const bfrag*)Bf0U;
    bfrag bfA[4][4], bfB[4][4];
    load_group(Bf0, 0, L, bfA);
    load_group(Bf0, 4, L, bfB);

    // A-frags: reads = sum of the WG2 scan partials, cast to bf16
    bfrag Rf[4];
    #pragma unroll
    for (int ki = 0; ki < 4; ki++) {
        const float* p0 = part_buf + (size_t)tokA * DS + ki * 32 + quad * 8;
        f32x4 x = (f32x4){0.f,0.f,0.f,0.f}, y = (f32x4){0.f,0.f,0.f,0.f};
        #pragma unroll
        for (int g = 0; g < WG2; g++) {
            const f32x4* q4 = (const f32x4*)(p0 + (size_t)g * NTOK * DS);
            x = x + q4[0]; y = y + q4[1];
        }
        Rf[ki] = mk_frag(x, y);
    }

    float f[4][8];   // [reg][nt]
    f32x4 acc[4];

    #pragma unroll
    for (int t = 0; t < 4; t++) acc[t] = (f32x4){0.f,0.f,0.f,0.f};
    mfma_group(Rf, bfA, acc);
    #pragma unroll
    for (int t = 0; t < 4; t++) {
        const int n = t * 16 + L15;
        const float fb = fB[n];
        #pragma unroll
        for (int reg = 0; reg < 4; reg++)
            f[reg][t] = fast_tanh(acc[t][reg] + kp_buf[(size_t)(tokD0 + reg) * DS + n] + fb);
    }

    #pragma unroll
    for (int t = 0; t < 4; t++) acc[t] = (f32x4){0.f,0.f,0.f,0.f};
    mfma_group(Rf, bfB, acc);
    #pragma unroll
    for (int t = 0; t < 4; t++) {
        const int n = (4 + t) * 16 + L15;
        const float fb = fB[n];
        #pragma unroll
        for (int reg = 0; reg < 4; reg++)
            f[reg][4 + t] = fast_tanh(acc[t][reg] + kp_buf[(size_t)(tokD0 + reg) * DS + n] + fb);
    }

    // pred: per D-row token, dot(f, pW[ix]) reduced over the 16 lanes (L15)
    #pragma unroll
    for (int reg = 0; reg < 4; reg++) {
        const int tok = tokD0 + reg;
        const int t = tok % Tn;
        const bool act = (t < Tn - 1);
        int sn = 0, ix = 0;
        float contrib = 0.f;
        if (act) {
            sn = skill[tok + 1];
            ix = (sn < NUMC) ? sn : (NUMC - 1);
            const float* pr = pW + (size_t)ix * DS + L15;
            #pragma unroll
            for (int nt = 0; nt < 8; nt++)
                contrib = fmaf(f[reg][nt], pr[nt * 16], contrib);
        }
        #pragma unroll
        for (int msk = 1; msk <= 8; msk <<= 1)
            contrib += __shfl_xor(contrib, msk);
        if (act && L15 == 0) {
            const float val = contrib + pB[ix];
            const float prd = (sn < NUMC) ? fast_sigmoid(val) : 0.f;
            out[(size_t)(tok / Tn) * (Tn - 1) + t] = prd;
        }
    }
}

extern "C" void kernel_launch(void* const* d_in, const int* in_sizes, int n_in,
                              void* d_out, int out_size, void* d_ws, size_t ws_size,
                              hipStream_t stream)
{
    const int*   skill  = (const int*)  d_in[0];
    const int*   answer = (const int*)  d_in[1];
    const float* k_emb  = (const float*)d_in[2];
    const float* v_emb  = (const float*)d_in[3];
    const float* Mk     = (const float*)d_in[4];
    const float* Mv0    = (const float*)d_in[5];
    const float* f_W    = (const float*)d_in[6];
    const float* f_b    = (const float*)d_in[7];
    const float* p_W    = (const float*)d_in[8];
    const float* p_b    = (const float*)d_in[9];
    const float* e_W    = (const float*)d_in[10];
    const float* e_b    = (const float*)d_in[11];
    const float* a_W    = (const float*)d_in[12];
    const float* a_b    = (const float*)d_in[13];
    float* out = (float*)d_out;

    float* ws       = (float*)d_ws;
    float* w_buf    = ws;                                  // NTOK*SM
    float* e_buf    = w_buf    + (size_t)NTOK*SM;
    float* a_buf    = e_buf    + (size_t)NTOK*DS;
    float* kp_buf   = a_buf    + (size_t)NTOK*DS;
    float* part_buf = kp_buf   + (size_t)NTOK*DS;          // WG2*NTOK*DS
    unsigned int* BeaU = (unsigned int*)(part_buf + (size_t)WG2*NTOK*DS);
    unsigned int* BkmU = BeaU + 4096 * 4;
    unsigned int* Bf0U = BkmU + 3072 * 4;

    k0_cast<<<36, 256, 0, stream>>>(e_W, a_W, f_W, Mk, BeaU, BkmU, Bf0U);
    k1_gemm<<<2*(NTOK/16), 64, 0, stream>>>(skill, answer, k_emb, v_emb,
        BeaU, BkmU, e_b, a_b, w_buf, e_buf, a_buf, kp_buf);
    k2_scan<<<Bsz*2*WG2, 64, 0, stream>>>(w_buf, e_buf, a_buf, Mv0, part_buf);
    k3_gemm<<<NTOK/16, 64, 0, stream>>>(part_buf, kp_buf, Bf0U, f_b,
        p_W, p_b, skill, out);
}